// Round 18
// baseline (83.853 us; speedup 1.0000x reference)
//
#include <hip/hip_runtime.h>

#define NN 8192
#define EE 256
#define KNH 32
#define NKEEP 4096
#define NCX 64
#define NCELL 4096
#define CNT_MIN 48

typedef unsigned long long u64;
typedef unsigned int u32;

// ws layout:
// part  @ 0      [2][32][256] f32   (65536)
// gm    @ 65536  [2][256] f32       ( 2048)
// start @ 67584  [2][4097] int      (32800 alloc)
// sc    @ 100384 [2][8192] float2   (131072)
// sj    @ 231456 [2][8192] int      (65536)   -> 296992 total

__device__ __forceinline__ int cellof(float v) {
    const int q = (int)floorf((v + 4.6f) * (64.0f / 9.2f));
    return min(max(q, 0), NCX - 1);
}

// fused: blocks 0-1 = per-batch binning (count -> wave-scan -> scatter);
// blocks 2-65 = gm column-sum, ONE (b,chunk) unit per 1024-thread block
// (4 threads/column x 64 rows each + deterministic 4-way LDS reduce).
__global__ void __launch_bounds__(1024) k_pre(const float* __restrict__ coords,
                                              const float* __restrict__ x,
                                              int* __restrict__ start,
                                              float2* __restrict__ sc,
                                              int* __restrict__ sj,
                                              float* __restrict__ part) {
    __shared__ int cnt[NCELL];
    __shared__ int wsum[16];
    const int blk = blockIdx.x;
    if (blk >= 2) {
        float* fred = (float*)cnt;            // reuse LDS as f32 reduce buffer
        const int unit  = blk - 2;            // 0..63
        const int b     = unit >> 5;
        const int chunk = unit & 31;
        const int col   = threadIdx.x & 255;
        const int qtr   = threadIdx.x >> 8;   // 0..3
        const float* xp = x + ((size_t)b * NN + (size_t)chunk * 256 + (size_t)qtr * 64) * EE + col;
        float s = 0.0f;
        for (int r = 0; r < 64; ++r) s += xp[(size_t)r * EE];
        fred[threadIdx.x] = s;
        __syncthreads();
        if (threadIdx.x < 256) {
            const float tot = fred[threadIdx.x] + fred[threadIdx.x + 256]
                            + fred[threadIdx.x + 512] + fred[threadIdx.x + 768];
            part[((size_t)b * 32 + chunk) * EE + threadIdx.x] = tot;
        }
        return;
    }
    const int b = blk, t = threadIdx.x;
    const int lane = t & 63, wv = t >> 6;
#pragma unroll
    for (int k = 0; k < 4; ++k) cnt[k * 1024 + t] = 0;
    __syncthreads();
#pragma unroll
    for (int k = 0; k < 8; ++k) {
        const int i = k * 1024 + t;
        const float xv = coords[(size_t)b * 2 * NN + i];
        const float yv = coords[(size_t)b * 2 * NN + NN + i];
        atomicAdd(&cnt[cellof(xv) * NCX + cellof(yv)], 1);
    }
    __syncthreads();
    const int v0 = cnt[t * 4 + 0], v1 = cnt[t * 4 + 1];
    const int v2 = cnt[t * 4 + 2], v3 = cnt[t * 4 + 3];
    const int s = v0 + v1 + v2 + v3;
    int inc = s;
#pragma unroll
    for (int d = 1; d < 64; d <<= 1) {
        const int u = __shfl_up(inc, d);
        inc += (lane >= d) ? u : 0;
    }
    if (lane == 63) wsum[wv] = inc;
    __syncthreads();
    int wpre = 0;
#pragma unroll
    for (int w = 0; w < 16; ++w) wpre += (w < wv) ? wsum[w] : 0;
    int run = wpre + inc - s;
    start[b * (NCELL + 1) + t * 4 + 0] = run; cnt[t * 4 + 0] = run; run += v0;
    start[b * (NCELL + 1) + t * 4 + 1] = run; cnt[t * 4 + 1] = run; run += v1;
    start[b * (NCELL + 1) + t * 4 + 2] = run; cnt[t * 4 + 2] = run; run += v2;
    start[b * (NCELL + 1) + t * 4 + 3] = run; cnt[t * 4 + 3] = run; run += v3;
    if (t == 0) start[b * (NCELL + 1) + NCELL] = NN;
    __syncthreads();
#pragma unroll
    for (int k = 0; k < 8; ++k) {
        const int i = k * 1024 + t;
        const float xv = coords[(size_t)b * 2 * NN + i];
        const float yv = coords[(size_t)b * 2 * NN + NN + i];
        const int p = atomicAdd(&cnt[cellof(xv) * NCX + cellof(yv)], 1);
        sc[(size_t)b * NN + p] = make_float2(xv, yv);
        sj[(size_t)b * NN + p] = i;
    }
}

__global__ void k_gm_final(const float* __restrict__ part, float* __restrict__ gm) {
    const int b = blockIdx.y, t = threadIdx.x;
    float s = 0.0f;
    for (int c = 0; c < 32; ++c) s += part[((size_t)b * 32 + c) * EE + t];
    gm[b * EE + t] = fabsf(s / (float)NN);
}

__device__ __forceinline__ u64 shfl_xor_u64(u64 v, int m) {
    const u32 hi = (u32)__shfl_xor((int)(u32)(v >> 32), m);
    const u32 lo = (u32)__shfl_xor((int)(u32)v, m);
    return ((u64)hi << 32) | lo;
}

__device__ __forceinline__ u64 wave_min_u64(u64 h) {
#pragma unroll
    for (int s = 1; s < 64; s <<= 1) {
        const u64 o = shfl_xor_u64(h, s);
        h = (o < h) ? o : h;
    }
    return h;
}

// Round-17 kernel (measured 46.3 us): speculative r=1/2/4 box, 2x-unrolled
// chunk loops, bitonic T + survivor sort, certificates -> exact fallback.
__global__ void __launch_bounds__(256) k_knn_dist(
        const float* __restrict__ x,
        const float* __restrict__ gm, const float2* __restrict__ sc,
        const int* __restrict__ sj, const int* __restrict__ start,
        float* __restrict__ ld_out) {
    __shared__ u64 comp[4][64];
    const int wg   = blockIdx.x;               // 0..4095
    const int swz  = (wg & 7) * 512 + (wg >> 3);   // contiguous span per XCD
    const int b    = swz >> 11;
    const int pb   = swz & 2047;
    const int wid  = threadIdx.x >> 6;
    const int lane = threadIdx.x & 63;
    const int p    = pb * 4 + wid;

    const float2* scb = sc + (size_t)b * NN;
    const int*    sjb = sj + (size_t)b * NN;
    const int*    stb = start + b * (NCELL + 1);
    const float2 cp = scb[p];
    const int    i  = sjb[p];
    const float ci0 = cp.x, ci1 = cp.y;
    const int qx = cellof(ci0), qy = cellof(ci1);

    // ---- adaptive square: speculative r=1,2,4, else doubling from 8 ----
    int xl, yl, yh, nsl;
    int myc0 = 0, mylen = 0;
    {
        const int xl0 = max(qx - 1, 0), xh0 = min(qx + 1, NCX - 1);
        const int yl0 = max(qy - 1, 0), yh0 = min(qy + 1, NCX - 1);
        const int ns0 = xh0 - xl0 + 1;
        int a0 = 0, a1 = 0;
        if (lane < ns0) { a0 = stb[(xl0 + lane) * NCX + yl0]; a1 = stb[(xl0 + lane) * NCX + yh0 + 1]; }
        const int xl1 = max(qx - 2, 0), xh1 = min(qx + 2, NCX - 1);
        const int yl1 = max(qy - 2, 0), yh1 = min(qy + 2, NCX - 1);
        const int ns1 = xh1 - xl1 + 1;
        int b0 = 0, b1 = 0;
        if (lane < ns1) { b0 = stb[(xl1 + lane) * NCX + yl1]; b1 = stb[(xl1 + lane) * NCX + yh1 + 1]; }
        const int xl2 = max(qx - 4, 0), xh2c = min(qx + 4, NCX - 1);
        const int yl2 = max(qy - 4, 0), yh2c = min(qy + 4, NCX - 1);
        const int ns2 = xh2c - xl2 + 1;
        int e0 = 0, e1 = 0;
        if (lane < ns2) { e0 = stb[(xl2 + lane) * NCX + yl2]; e1 = stb[(xl2 + lane) * NCX + yh2c + 1]; }

        const int l0 = a1 - a0, l1 = b1 - b0, l2 = e1 - e0;
        int t0 = l0, t1 = l1, t2 = l2;
#pragma unroll
        for (int s = 1; s < 64; s <<= 1) {
            t0 += __shfl_xor(t0, s);
            t1 += __shfl_xor(t1, s);
            t2 += __shfl_xor(t2, s);
        }
        if (t0 >= CNT_MIN) {
            xl = xl0; yl = yl0; yh = yh0; nsl = ns0; myc0 = a0; mylen = l0;
        } else if (t1 >= CNT_MIN) {
            xl = xl1; yl = yl1; yh = yh1; nsl = ns1; myc0 = b0; mylen = l1;
        } else if (t2 >= CNT_MIN) {
            xl = xl2; yl = yl2; yh = yh2c; nsl = ns2; myc0 = e0; mylen = l2;
        } else {
            int r = 8;
            for (;;) {
                xl = max(qx - r, 0);
                const int xh = min(qx + r, NCX - 1);
                yl = max(qy - r, 0);
                yh = min(qy + r, NCX - 1);
                nsl = xh - xl + 1;
                int c0 = 0, c1 = 0;
                if (lane < nsl) {
                    c0 = stb[(xl + lane) * NCX + yl];
                    c1 = stb[(xl + lane) * NCX + yh + 1];
                }
                myc0 = c0; mylen = c1 - c0;
                int tot = mylen;
#pragma unroll
                for (int s = 1; s < 64; s <<= 1) tot += __shfl_xor(tot, s);
                if (tot >= CNT_MIN || r >= NCX) break;
                r <<= 1;
            }
        }
    }
    int incl = mylen;
#pragma unroll
    for (int d = 1; d < 64; d <<= 1) {
        const int v = __shfl_up(incl, d);
        incl += (lane >= d) ? v : 0;
    }
    int excl = incl - mylen;
    const int L1 = __shfl(incl, 63);

    // ---- pass 1: per-lane min, 2x-unrolled chunks ----
    float dmin = 1e30f;
    for (int g = 0; g < L1; g += 128) {
        const int gp0 = g + lane;
        const int gp1 = g + 64 + lane;
        int lo0 = 0, hi0 = nsl - 1, lo1 = 0, hi1 = nsl - 1;
#pragma unroll
        for (int st = 0; st < 6; ++st) {
            const int mid0 = (lo0 + hi0 + 1) >> 1;
            const int mid1 = (lo1 + hi1 + 1) >> 1;
            const int v0 = __shfl(excl, mid0);
            const int v1 = __shfl(excl, mid1);
            const bool go0 = (v0 <= gp0), go1 = (v1 <= gp1);
            lo0 = go0 ? mid0 : lo0; hi0 = go0 ? hi0 : mid0 - 1;
            lo1 = go1 ? mid1 : lo1; hi1 = go1 ? hi1 : mid1 - 1;
        }
        const int cnd0 = __shfl(myc0, lo0) + gp0 - __shfl(excl, lo0);
        const int cnd1 = __shfl(myc0, lo1) + gp1 - __shfl(excl, lo1);
        const int cc0 = min(max(cnd0, 0), NN - 1);
        const int cc1 = min(max(cnd1, 0), NN - 1);
        const float2 pt0 = scb[cc0];
        const float2 pt1 = scb[cc1];
        const float dx0 = ci0 - pt0.x, dy0 = ci1 - pt0.y;
        const float dx1 = ci0 - pt1.x, dy1 = ci1 - pt1.y;
        const float d0 = fmaf(dx0, dx0, dy0 * dy0);
        const float d1 = fmaf(dx1, dx1, dy1 * dy1);
        if (gp0 < L1) dmin = fminf(dmin, d0);
        if (gp1 < L1) dmin = fminf(dmin, d1);
    }

    // ---- T = 32nd smallest of the 64 lane minima (u32 bitonic sort) ----
    u32 mk = __float_as_uint(dmin);
#pragma unroll
    for (int k = 2; k <= 64; k <<= 1) {
#pragma unroll
        for (int j = k >> 1; j > 0; j >>= 1) {
            const u32 o = (u32)__shfl_xor((int)mk, j);
            const bool keep_min = (((lane & j) == 0) == ((lane & k) == 0));
            const u32 mn = min(mk, o), mx = max(mk, o);
            mk = keep_min ? mn : mx;
        }
    }
    const u32 T = (u32)__shfl((int)mk, 31);

    // ---- pass 2: flatten the sqrt(T)-box, 2x-unrolled compact ----
    const float srad = sqrtf(__uint_as_float(T)) * 1.0002f + 1e-5f;
    xl = cellof(ci0 - srad);
    const int xh2 = cellof(ci0 + srad);
    yl = cellof(ci1 - srad);
    yh = cellof(ci1 + srad);
    nsl = xh2 - xl + 1;
    {
        int c0 = 0, c1 = 0;
        if (lane < nsl) {
            c0 = stb[(xl + lane) * NCX + yl];
            c1 = stb[(xl + lane) * NCX + yh + 1];
        }
        myc0 = c0; mylen = c1 - c0;
    }
    incl = mylen;
#pragma unroll
    for (int d = 1; d < 64; d <<= 1) {
        const int v = __shfl_up(incl, d);
        incl += (lane >= d) ? v : 0;
    }
    excl = incl - mylen;
    const int L2 = __shfl(incl, 63);

    const u64 lmask = (1ull << lane) - 1;
    int base = 0;
    for (int g = 0; g < L2; g += 128) {
        const int gp0 = g + lane;
        const int gp1 = g + 64 + lane;
        int lo0 = 0, hi0 = nsl - 1, lo1 = 0, hi1 = nsl - 1;
#pragma unroll
        for (int st = 0; st < 6; ++st) {
            const int mid0 = (lo0 + hi0 + 1) >> 1;
            const int mid1 = (lo1 + hi1 + 1) >> 1;
            const int v0 = __shfl(excl, mid0);
            const int v1 = __shfl(excl, mid1);
            const bool go0 = (v0 <= gp0), go1 = (v1 <= gp1);
            lo0 = go0 ? mid0 : lo0; hi0 = go0 ? hi0 : mid0 - 1;
            lo1 = go1 ? mid1 : lo1; hi1 = go1 ? hi1 : mid1 - 1;
        }
        const int cnd0 = __shfl(myc0, lo0) + gp0 - __shfl(excl, lo0);
        const int cnd1 = __shfl(myc0, lo1) + gp1 - __shfl(excl, lo1);
        const int cc0 = min(max(cnd0, 0), NN - 1);
        const int cc1 = min(max(cnd1, 0), NN - 1);
        const float2 pt0 = scb[cc0];
        const float2 pt1 = scb[cc1];
        const int jj0 = sjb[cc0];
        const int jj1 = sjb[cc1];
        const float dx0 = ci0 - pt0.x, dy0 = ci1 - pt0.y;
        const float dx1 = ci0 - pt1.x, dy1 = ci1 - pt1.y;
        const u32 db0 = __float_as_uint(fmaf(dx0, dx0, dy0 * dy0));
        const u32 db1 = __float_as_uint(fmaf(dx1, dx1, dy1 * dy1));
        const bool k0 = (gp0 < L2) && (db0 <= T);
        const bool k1 = (gp1 < L2) && (db1 <= T);
        const u64 m0 = __ballot(k0);
        const int pos0 = base + __popcll(m0 & lmask);
        base += __popcll(m0);
        if (k0 && pos0 < 64) comp[wid][pos0] = ((u64)db0 << 32) | (u32)jj0;
        const u64 m1 = __ballot(k1);
        const int pos1 = base + __popcll(m1 & lmask);
        base += __popcll(m1);
        if (k1 && pos1 < 64) comp[wid][pos1] = ((u64)db1 << 32) | (u32)jj1;
    }
    const bool ovf = (base > 64) || (base < KNH);

    // ---- bitonic sort (ascending) of up to 64 survivor keys ----
    u64 key = (lane < base) ? comp[wid][lane] : ~0ull;
#pragma unroll
    for (int k = 2; k <= 64; k <<= 1) {
#pragma unroll
        for (int j = k >> 1; j > 0; j >>= 1) {
            const u64 other = shfl_xor_u64(key, j);
            const bool keep_min = (((lane & j) == 0) == ((lane & k) == 0));
            const bool lt = (key < other);
            const u64 mn = lt ? key : other;
            const u64 mx = lt ? other : key;
            key = keep_min ? mn : mx;
        }
    }
    int jkeep = (int)(u32)key;   // lane m (m<32) holds m-th nearest index

    // ---- certificate fallback: exact 32-round argmin over the stream ----
    if (ovf) {
        u64 minkeep = 0;
        for (int k = 0; k < KNH; ++k) {
            u64 best = ~0ull;
            for (int g = 0; g < L2; g += 64) {
                const int gp = g + lane;
                int lo = 0, hi = nsl - 1;
#pragma unroll
                for (int st = 0; st < 6; ++st) {
                    const int mid = (lo + hi + 1) >> 1;
                    const int v = __shfl(excl, mid);
                    const bool go = (v <= gp);
                    lo = go ? mid : lo;
                    hi = go ? hi : mid - 1;
                }
                const int cnd = __shfl(myc0, lo) + gp - __shfl(excl, lo);
                const int cc  = min(max(cnd, 0), NN - 1);
                const float2 pt = scb[cc];
                const int    jj = sjb[cc];
                const float dx = ci0 - pt.x, dy = ci1 - pt.y;
                const float d  = fmaf(dx, dx, dy * dy);
                const u64 kk = ((u64)__float_as_uint(d) << 32) | (u32)jj;
                if (gp < L2 && kk >= minkeep && kk < best) best = kk;
            }
            const u64 h = wave_min_u64(best);
            if (lane == k) jkeep = (int)(u32)h;
            minkeep = h + 1;
        }
    }

    // ---- gather 32 rows, f32 sum/sumsq (4 channels per lane) ----
    float s1[4] = {0.f, 0.f, 0.f, 0.f};
    float s2[4] = {0.f, 0.f, 0.f, 0.f};
    const float* xb = x + (size_t)b * NN * EE;
#pragma unroll 8
    for (int k = 0; k < KNH; ++k) {
        const int j = __builtin_amdgcn_readlane(jkeep, k);
        const float4 v = *reinterpret_cast<const float4*>(xb + (size_t)j * EE + (lane << 2));
        s1[0] += v.x; s2[0] += v.x * v.x;
        s1[1] += v.y; s2[1] += v.y * v.y;
        s1[2] += v.z; s2[2] += v.z * v.z;
        s1[3] += v.w; s2[3] += v.w * v.w;
    }

    const float* gmb = gm + b * EE;
    float tt = 0.f;
#pragma unroll
    for (int q = 0; q < 4; ++q) {
        const float sum = s1[q];
        float ssd = s2[q] - sum * sum * (1.0f / 32.0f);
        ssd = ssd > 0.f ? ssd : 0.f;
        const float ls = sqrtf(ssd * (1.0f / 31.0f));
        tt += ls / gmb[(lane << 2) + q];
    }
#pragma unroll
    for (int s2r = 1; s2r < 64; s2r <<= 1) tt += __shfl_xor(tt, s2r);

    if (lane == 0) ld_out[(size_t)b * NN + i] = tt;
}

// one wave per point: exact rank (desc, index tie-break) + direct row gather
__global__ void k_rank_gather(const float* __restrict__ x, const float* __restrict__ coords,
                              const float* __restrict__ ld,
                              float* __restrict__ x_out, float* __restrict__ c_out) {
    const int b    = blockIdx.y;
    const int wid  = threadIdx.x >> 6;
    const int lane = threadIdx.x & 63;
    const int i    = blockIdx.x * 4 + wid;
    const float* lb = ld + (size_t)b * NN;
    const float di = lb[i];
    int cnt = 0;
    for (int t = 0; t < NN / 256; ++t) {
        const int j0 = t * 256 + (lane << 2);
        const float4 dv = *reinterpret_cast<const float4*>(lb + j0);
        cnt += (dv.x > di || (dv.x == di && (j0 + 0) < i)) ? 1 : 0;
        cnt += (dv.y > di || (dv.y == di && (j0 + 1) < i)) ? 1 : 0;
        cnt += (dv.z > di || (dv.z == di && (j0 + 2) < i)) ? 1 : 0;
        cnt += (dv.w > di || (dv.w == di && (j0 + 3) < i)) ? 1 : 0;
    }
#pragma unroll
    for (int s = 1; s < 64; s <<= 1) cnt += __shfl_xor(cnt, s);

    if (cnt < NKEEP) {
        const float4 v = *reinterpret_cast<const float4*>(x + ((size_t)b * NN + i) * EE + (lane << 2));
        *reinterpret_cast<float4*>(x_out + ((size_t)b * NKEEP + cnt) * EE + (lane << 2)) = v;
        if (lane < 2) {
            c_out[((size_t)b * 2 + lane) * NKEEP + cnt] = coords[((size_t)b * 2 + lane) * NN + i];
        }
    }
}

extern "C" void kernel_launch(void* const* d_in, const int* in_sizes, int n_in,
                              void* d_out, int out_size, void* d_ws, size_t ws_size,
                              hipStream_t stream) {
    const float* x      = (const float*)d_in[0];
    const float* coords = (const float*)d_in[1];

    float* out    = (float*)d_out;
    float* x_out  = out;                 // [2][4096][256]
    float* c_out  = out + 2097152;       // [2][2][4096][1]
    float* ld_out = out + 2113536;       // [2][8192]

    char*   ws    = (char*)d_ws;
    float*  part  = (float*)(ws);
    float*  gm    = (float*)(ws + 65536);
    int*    start = (int*)  (ws + 67584);
    float2* sc    = (float2*)(ws + 100384);
    int*    sj    = (int*)  (ws + 231456);

    k_pre        <<<66,            1024, 0, stream>>>(coords, x, start, sc, sj, part);
    k_gm_final   <<<dim3(1, 2),    256,  0, stream>>>(part, gm);
    k_knn_dist   <<<4096,          256,  0, stream>>>(x, gm, sc, sj, start, ld_out);
    k_rank_gather<<<dim3(2048, 2), 256,  0, stream>>>(x, coords, ld_out, x_out, c_out);
}

// Round 19
// 82.862 us; speedup vs baseline: 1.0120x; 1.0120x over previous
//
#include <hip/hip_runtime.h>

#define NN 8192
#define EE 256
#define KNH 32
#define NKEEP 4096
#define NCX 64
#define NCELL 4096
#define CNT_MIN 48

typedef unsigned long long u64;
typedef unsigned int u32;

// ws layout:
// part  @ 0      [2][32][256] f32   (65536)
// gm    @ 65536  [2][256] f32       ( 2048)
// start @ 67584  [2][4097] int      (32800 alloc)
// sc    @ 100384 [2][8192] float2   (131072)
// sj    @ 231456 [2][8192] int      (65536)   -> 296992 total

__device__ __forceinline__ int cellof(float v) {
    const int q = (int)floorf((v + 4.6f) * (64.0f / 9.2f));
    return min(max(q, 0), NCX - 1);
}

// fused: blocks 0-1 = per-batch binning; blocks 2-65 = gm column-sum units.
__global__ void __launch_bounds__(1024) k_pre(const float* __restrict__ coords,
                                              const float* __restrict__ x,
                                              int* __restrict__ start,
                                              float2* __restrict__ sc,
                                              int* __restrict__ sj,
                                              float* __restrict__ part) {
    __shared__ int cnt[NCELL];
    __shared__ int wsum[16];
    const int blk = blockIdx.x;
    if (blk >= 2) {
        float* fred = (float*)cnt;
        const int unit  = blk - 2;
        const int b     = unit >> 5;
        const int chunk = unit & 31;
        const int col   = threadIdx.x & 255;
        const int qtr   = threadIdx.x >> 8;
        const float* xp = x + ((size_t)b * NN + (size_t)chunk * 256 + (size_t)qtr * 64) * EE + col;
        float s = 0.0f;
        for (int r = 0; r < 64; ++r) s += xp[(size_t)r * EE];
        fred[threadIdx.x] = s;
        __syncthreads();
        if (threadIdx.x < 256) {
            const float tot = fred[threadIdx.x] + fred[threadIdx.x + 256]
                            + fred[threadIdx.x + 512] + fred[threadIdx.x + 768];
            part[((size_t)b * 32 + chunk) * EE + threadIdx.x] = tot;
        }
        return;
    }
    const int b = blk, t = threadIdx.x;
    const int lane = t & 63, wv = t >> 6;
#pragma unroll
    for (int k = 0; k < 4; ++k) cnt[k * 1024 + t] = 0;
    __syncthreads();
#pragma unroll
    for (int k = 0; k < 8; ++k) {
        const int i = k * 1024 + t;
        const float xv = coords[(size_t)b * 2 * NN + i];
        const float yv = coords[(size_t)b * 2 * NN + NN + i];
        atomicAdd(&cnt[cellof(xv) * NCX + cellof(yv)], 1);
    }
    __syncthreads();
    const int v0 = cnt[t * 4 + 0], v1 = cnt[t * 4 + 1];
    const int v2 = cnt[t * 4 + 2], v3 = cnt[t * 4 + 3];
    const int s = v0 + v1 + v2 + v3;
    int inc = s;
#pragma unroll
    for (int d = 1; d < 64; d <<= 1) {
        const int u = __shfl_up(inc, d);
        inc += (lane >= d) ? u : 0;
    }
    if (lane == 63) wsum[wv] = inc;
    __syncthreads();
    int wpre = 0;
#pragma unroll
    for (int w = 0; w < 16; ++w) wpre += (w < wv) ? wsum[w] : 0;
    int run = wpre + inc - s;
    start[b * (NCELL + 1) + t * 4 + 0] = run; cnt[t * 4 + 0] = run; run += v0;
    start[b * (NCELL + 1) + t * 4 + 1] = run; cnt[t * 4 + 1] = run; run += v1;
    start[b * (NCELL + 1) + t * 4 + 2] = run; cnt[t * 4 + 2] = run; run += v2;
    start[b * (NCELL + 1) + t * 4 + 3] = run; cnt[t * 4 + 3] = run; run += v3;
    if (t == 0) start[b * (NCELL + 1) + NCELL] = NN;
    __syncthreads();
#pragma unroll
    for (int k = 0; k < 8; ++k) {
        const int i = k * 1024 + t;
        const float xv = coords[(size_t)b * 2 * NN + i];
        const float yv = coords[(size_t)b * 2 * NN + NN + i];
        const int p = atomicAdd(&cnt[cellof(xv) * NCX + cellof(yv)], 1);
        sc[(size_t)b * NN + p] = make_float2(xv, yv);
        sj[(size_t)b * NN + p] = i;
    }
}

__global__ void k_gm_final(const float* __restrict__ part, float* __restrict__ gm) {
    const int b = blockIdx.y, t = threadIdx.x;
    float s = 0.0f;
    for (int c = 0; c < 32; ++c) s += part[((size_t)b * 32 + c) * EE + t];
    gm[b * EE + t] = fabsf(s / (float)NN);
}

__device__ __forceinline__ u64 shfl_xor_u64(u64 v, int m) {
    const u32 hi = (u32)__shfl_xor((int)(u32)(v >> 32), m);
    const u32 lo = (u32)__shfl_xor((int)(u32)v, m);
    return ((u64)hi << 32) | lo;
}

__device__ __forceinline__ u64 wave_min_u64(u64 h) {
#pragma unroll
    for (int s = 1; s < 64; s <<= 1) {
        const u64 o = shfl_xor_u64(h, s);
        h = (o < h) ? o : h;
    }
    return h;
}

// exact 32-round argmin over a cell box (rare certificate fallback)
__device__ __noinline__ int exact_fb(const float2* scb, const int* sjb, const int* stb,
                                     float cx, float cy, int xl, int xh, int yl, int yh,
                                     int lane) {
    const int nsl = xh - xl + 1;
    int c0 = 0, c1 = 0;
    if (lane < nsl) { c0 = stb[(xl + lane) * NCX + yl]; c1 = stb[(xl + lane) * NCX + yh + 1]; }
    const int myc = c0, len = c1 - c0;
    int inc = len;
#pragma unroll
    for (int d = 1; d < 64; d <<= 1) {
        const int v = __shfl_up(inc, d);
        inc += (lane >= d) ? v : 0;
    }
    const int ex = inc - len;
    const int L = __shfl(inc, 63);
    int jk = 0;
    u64 minkeep = 0;
    for (int k = 0; k < KNH; ++k) {
        u64 best = ~0ull;
        for (int g = 0; g < L; g += 64) {
            const int gp = g + lane;
            int lo = 0, hi = nsl - 1;
#pragma unroll
            for (int st = 0; st < 6; ++st) {
                const int mid = (lo + hi + 1) >> 1;
                const int v = __shfl(ex, mid);
                const bool go = (v <= gp);
                lo = go ? mid : lo;
                hi = go ? hi : mid - 1;
            }
            const int cnd = __shfl(myc, lo) + gp - __shfl(ex, lo);
            const int cc = min(max(cnd, 0), NN - 1);
            const float2 pt = scb[cc];
            const int jj = sjb[cc];
            const float dx = cx - pt.x, dy = cy - pt.y;
            const float d = fmaf(dx, dx, dy * dy);
            const u64 kk = ((u64)__float_as_uint(d) << 32) | (u32)jj;
            if (gp < L && kk >= minkeep && kk < best) best = kk;
        }
        const u64 h = wave_min_u64(best);
        if (lane == k) jk = (int)(u32)h;
        minkeep = h + 1;
    }
    return jk;
}

// Round-17 structure + register-cached pass 1 (up to 256 cands in 8 named
// regs). Pass 2 = 4 ballot-compactions from registers when the sqrt(T)-box
// is contained in the pass-1 box (usual case); else global re-walk. Identical
// survivor set either way; ovf -> exact_fb over the pass-2 box.
__global__ void __launch_bounds__(256) k_knn_dist(
        const float* __restrict__ x,
        const float* __restrict__ gm, const float2* __restrict__ sc,
        const int* __restrict__ sj, const int* __restrict__ start,
        float* __restrict__ ld_out) {
    __shared__ u64 comp[4][64];
    const int wg   = blockIdx.x;               // 0..4095
    const int swz  = (wg & 7) * 512 + (wg >> 3);   // contiguous span per XCD
    const int b    = swz >> 11;
    const int pb   = swz & 2047;
    const int wid  = threadIdx.x >> 6;
    const int lane = threadIdx.x & 63;
    const int p    = pb * 4 + wid;

    const float2* scb = sc + (size_t)b * NN;
    const int*    sjb = sj + (size_t)b * NN;
    const int*    stb = start + b * (NCELL + 1);
    const float2 cp = scb[p];
    const int    i  = sjb[p];
    const float ci0 = cp.x, ci1 = cp.y;
    const int qx = cellof(ci0), qy = cellof(ci1);

    // ---- adaptive square: speculative r=1,2,4, else doubling from 8 ----
    int xl, yl, yh, nsl;
    int myc0 = 0, mylen = 0;
    {
        const int xl0 = max(qx - 1, 0), xh0 = min(qx + 1, NCX - 1);
        const int yl0 = max(qy - 1, 0), yh0 = min(qy + 1, NCX - 1);
        const int ns0 = xh0 - xl0 + 1;
        int a0 = 0, a1 = 0;
        if (lane < ns0) { a0 = stb[(xl0 + lane) * NCX + yl0]; a1 = stb[(xl0 + lane) * NCX + yh0 + 1]; }
        const int xl1 = max(qx - 2, 0), xh1 = min(qx + 2, NCX - 1);
        const int yl1 = max(qy - 2, 0), yh1 = min(qy + 2, NCX - 1);
        const int ns1 = xh1 - xl1 + 1;
        int b0 = 0, b1 = 0;
        if (lane < ns1) { b0 = stb[(xl1 + lane) * NCX + yl1]; b1 = stb[(xl1 + lane) * NCX + yh1 + 1]; }
        const int xl2 = max(qx - 4, 0), xh2c = min(qx + 4, NCX - 1);
        const int yl2 = max(qy - 4, 0), yh2c = min(qy + 4, NCX - 1);
        const int ns2 = xh2c - xl2 + 1;
        int e0 = 0, e1 = 0;
        if (lane < ns2) { e0 = stb[(xl2 + lane) * NCX + yl2]; e1 = stb[(xl2 + lane) * NCX + yh2c + 1]; }

        const int l0 = a1 - a0, l1 = b1 - b0, l2 = e1 - e0;
        int t0 = l0, t1 = l1, t2 = l2;
#pragma unroll
        for (int s = 1; s < 64; s <<= 1) {
            t0 += __shfl_xor(t0, s);
            t1 += __shfl_xor(t1, s);
            t2 += __shfl_xor(t2, s);
        }
        if (t0 >= CNT_MIN) {
            xl = xl0; yl = yl0; yh = yh0; nsl = ns0; myc0 = a0; mylen = l0;
        } else if (t1 >= CNT_MIN) {
            xl = xl1; yl = yl1; yh = yh1; nsl = ns1; myc0 = b0; mylen = l1;
        } else if (t2 >= CNT_MIN) {
            xl = xl2; yl = yl2; yh = yh2c; nsl = ns2; myc0 = e0; mylen = l2;
        } else {
            int r = 8;
            for (;;) {
                xl = max(qx - r, 0);
                const int xh = min(qx + r, NCX - 1);
                yl = max(qy - r, 0);
                yh = min(qy + r, NCX - 1);
                nsl = xh - xl + 1;
                int c0 = 0, c1 = 0;
                if (lane < nsl) {
                    c0 = stb[(xl + lane) * NCX + yl];
                    c1 = stb[(xl + lane) * NCX + yh + 1];
                }
                myc0 = c0; mylen = c1 - c0;
                int tot = mylen;
#pragma unroll
                for (int s = 1; s < 64; s <<= 1) tot += __shfl_xor(tot, s);
                if (tot >= CNT_MIN || r >= NCX) break;
                r <<= 1;
            }
        }
    }
    const int xh1box = xl + nsl - 1;
    int incl = mylen;
#pragma unroll
    for (int d = 1; d < 64; d <<= 1) {
        const int v = __shfl_up(incl, d);
        incl += (lane >= d) ? v : 0;
    }
    int excl = incl - mylen;
    const int L1 = __shfl(incl, 63);

    // ---- pass 1: per-lane min; cache (d_bits, j) for first 4 chunks ----
    float dmin = 1e30f;
    u32 kdb0 = 0xFFFFFFFFu, kdb1 = 0xFFFFFFFFu, kdb2 = 0xFFFFFFFFu, kdb3 = 0xFFFFFFFFu;
    int  kjj0 = 0, kjj1 = 0, kjj2 = 0, kjj3 = 0;

#define CHUNK2(G, DB0, JJ0, DB1, JJ1)                                       \
    do {                                                                    \
        const int gp0 = (G) + lane;                                         \
        const int gp1 = (G) + 64 + lane;                                    \
        int lo0 = 0, hi0 = nsl - 1, lo1 = 0, hi1 = nsl - 1;                 \
        _Pragma("unroll")                                                   \
        for (int st = 0; st < 6; ++st) {                                    \
            const int mid0 = (lo0 + hi0 + 1) >> 1;                          \
            const int mid1 = (lo1 + hi1 + 1) >> 1;                          \
            const int v0 = __shfl(excl, mid0);                              \
            const int v1 = __shfl(excl, mid1);                              \
            const bool go0 = (v0 <= gp0), go1 = (v1 <= gp1);                \
            lo0 = go0 ? mid0 : lo0; hi0 = go0 ? hi0 : mid0 - 1;             \
            lo1 = go1 ? mid1 : lo1; hi1 = go1 ? hi1 : mid1 - 1;             \
        }                                                                   \
        const int cnd0 = __shfl(myc0, lo0) + gp0 - __shfl(excl, lo0);       \
        const int cnd1 = __shfl(myc0, lo1) + gp1 - __shfl(excl, lo1);       \
        const int cc0 = min(max(cnd0, 0), NN - 1);                          \
        const int cc1 = min(max(cnd1, 0), NN - 1);                          \
        const float2 pt0 = scb[cc0];                                        \
        const float2 pt1 = scb[cc1];                                        \
        const int j0_ = sjb[cc0];                                           \
        const int j1_ = sjb[cc1];                                           \
        const float dx0 = ci0 - pt0.x, dy0 = ci1 - pt0.y;                   \
        const float dx1 = ci0 - pt1.x, dy1 = ci1 - pt1.y;                   \
        const float d0 = fmaf(dx0, dx0, dy0 * dy0);                         \
        const float d1 = fmaf(dx1, dx1, dy1 * dy1);                         \
        if (gp0 < L1) { dmin = fminf(dmin, d0); DB0 = __float_as_uint(d0); JJ0 = j0_; } \
        if (gp1 < L1) { dmin = fminf(dmin, d1); DB1 = __float_as_uint(d1); JJ1 = j1_; } \
    } while (0)

    CHUNK2(0, kdb0, kjj0, kdb1, kjj1);
    if (L1 > 128) CHUNK2(128, kdb2, kjj2, kdb3, kjj3);
    for (int g = 256; g < L1; g += 128) {
        const int gp0 = g + lane;
        const int gp1 = g + 64 + lane;
        int lo0 = 0, hi0 = nsl - 1, lo1 = 0, hi1 = nsl - 1;
#pragma unroll
        for (int st = 0; st < 6; ++st) {
            const int mid0 = (lo0 + hi0 + 1) >> 1;
            const int mid1 = (lo1 + hi1 + 1) >> 1;
            const int v0 = __shfl(excl, mid0);
            const int v1 = __shfl(excl, mid1);
            const bool go0 = (v0 <= gp0), go1 = (v1 <= gp1);
            lo0 = go0 ? mid0 : lo0; hi0 = go0 ? hi0 : mid0 - 1;
            lo1 = go1 ? mid1 : lo1; hi1 = go1 ? hi1 : mid1 - 1;
        }
        const int cnd0 = __shfl(myc0, lo0) + gp0 - __shfl(excl, lo0);
        const int cnd1 = __shfl(myc0, lo1) + gp1 - __shfl(excl, lo1);
        const int cc0 = min(max(cnd0, 0), NN - 1);
        const int cc1 = min(max(cnd1, 0), NN - 1);
        const float2 pt0 = scb[cc0];
        const float2 pt1 = scb[cc1];
        const float dx0 = ci0 - pt0.x, dy0 = ci1 - pt0.y;
        const float dx1 = ci0 - pt1.x, dy1 = ci1 - pt1.y;
        const float d0 = fmaf(dx0, dx0, dy0 * dy0);
        const float d1 = fmaf(dx1, dx1, dy1 * dy1);
        if (gp0 < L1) dmin = fminf(dmin, d0);
        if (gp1 < L1) dmin = fminf(dmin, d1);
    }

    // ---- T = 32nd smallest of the 64 lane minima (u32 bitonic sort) ----
    u32 mk = __float_as_uint(dmin);
#pragma unroll
    for (int k = 2; k <= 64; k <<= 1) {
#pragma unroll
        for (int j = k >> 1; j > 0; j >>= 1) {
            const u32 o = (u32)__shfl_xor((int)mk, j);
            const bool keep_min = (((lane & j) == 0) == ((lane & k) == 0));
            const u32 mn = min(mk, o), mx = max(mk, o);
            mk = keep_min ? mn : mx;
        }
    }
    const u32 T = (u32)__shfl((int)mk, 31);

    // ---- pass-2 box; containment test vs pass-1 box ----
    const float srad = sqrtf(__uint_as_float(T)) * 1.0002f + 1e-5f;
    const int p2xl = cellof(ci0 - srad), p2xh = cellof(ci0 + srad);
    const int p2yl = cellof(ci1 - srad), p2yh = cellof(ci1 + srad);
    const bool contained = (L1 <= 256) && (p2xl >= xl) && (p2xh <= xh1box) &&
                           (p2yl >= yl) && (p2yh <= yh);

    const u64 lmask = (1ull << lane) - 1;
    int base = 0;

#define COMPACT(DB, JJ)                                                     \
    do {                                                                    \
        const bool keep = ((DB) <= T);                                      \
        const u64 m = __ballot(keep);                                       \
        const int pos = base + __popcll(m & lmask);                         \
        base += __popcll(m);                                                \
        if (keep && pos < 64) comp[wid][pos] = ((u64)(DB) << 32) | (u32)(JJ); \
    } while (0)

    if (contained) {
        // survivors straight from registers (set identical: any d<=T point
        // lies in the sqrt(T)-disk => inside pass-2 box => inside pass-1 box)
        COMPACT(kdb0, kjj0);
        COMPACT(kdb1, kjj1);
        COMPACT(kdb2, kjj2);
        COMPACT(kdb3, kjj3);
    } else {
        const int nsl2 = p2xh - p2xl + 1;
        int c0 = 0, c1 = 0;
        if (lane < nsl2) {
            c0 = stb[(p2xl + lane) * NCX + p2yl];
            c1 = stb[(p2xl + lane) * NCX + p2yh + 1];
        }
        const int myc2 = c0;
        const int len2 = c1 - c0;
        int incl2 = len2;
#pragma unroll
        for (int d = 1; d < 64; d <<= 1) {
            const int v = __shfl_up(incl2, d);
            incl2 += (lane >= d) ? v : 0;
        }
        const int excl2 = incl2 - len2;
        const int L2 = __shfl(incl2, 63);
        for (int g = 0; g < L2; g += 64) {
            const int gp = g + lane;
            int lo = 0, hi = nsl2 - 1;
#pragma unroll
            for (int st = 0; st < 6; ++st) {
                const int mid = (lo + hi + 1) >> 1;
                const int v = __shfl(excl2, mid);
                const bool go = (v <= gp);
                lo = go ? mid : lo;
                hi = go ? hi : mid - 1;
            }
            const int cnd = __shfl(myc2, lo) + gp - __shfl(excl2, lo);
            const int cc  = min(max(cnd, 0), NN - 1);
            const float2 pt = scb[cc];
            const int    jj = sjb[cc];
            const float dx = ci0 - pt.x, dy = ci1 - pt.y;
            const u32 db = __float_as_uint(fmaf(dx, dx, dy * dy));
            const bool keep = (gp < L2) && (db <= T);
            const u64 m = __ballot(keep);
            const int pos = base + __popcll(m & lmask);
            base += __popcll(m);
            if (keep && pos < 64) comp[wid][pos] = ((u64)db << 32) | (u32)jj;
        }
    }
    const bool ovf = (base > 64) || (base < KNH);

    // ---- bitonic sort (ascending) of up to 64 survivor keys ----
    u64 key = (lane < base) ? comp[wid][lane] : ~0ull;
#pragma unroll
    for (int k = 2; k <= 64; k <<= 1) {
#pragma unroll
        for (int j = k >> 1; j > 0; j >>= 1) {
            const u64 other = shfl_xor_u64(key, j);
            const bool keep_min = (((lane & j) == 0) == ((lane & k) == 0));
            const bool lt = (key < other);
            const u64 mn = lt ? key : other;
            const u64 mx = lt ? other : key;
            key = keep_min ? mn : mx;
        }
    }
    int jkeep = (int)(u32)key;   // lane m (m<32) holds m-th nearest index

    // ---- certificate fallback: exact argmin over the pass-2 box ----
    if (ovf) jkeep = exact_fb(scb, sjb, stb, ci0, ci1, p2xl, p2xh, p2yl, p2yh, lane);

    // ---- gather 32 rows, f32 sum/sumsq (4 channels per lane) ----
    float s1[4] = {0.f, 0.f, 0.f, 0.f};
    float s2[4] = {0.f, 0.f, 0.f, 0.f};
    const float* xb = x + (size_t)b * NN * EE;
#pragma unroll 8
    for (int k = 0; k < KNH; ++k) {
        const int j = __builtin_amdgcn_readlane(jkeep, k);
        const float4 v = *reinterpret_cast<const float4*>(xb + (size_t)j * EE + (lane << 2));
        s1[0] += v.x; s2[0] += v.x * v.x;
        s1[1] += v.y; s2[1] += v.y * v.y;
        s1[2] += v.z; s2[2] += v.z * v.z;
        s1[3] += v.w; s2[3] += v.w * v.w;
    }

    const float* gmb = gm + b * EE;
    float tt = 0.f;
#pragma unroll
    for (int q = 0; q < 4; ++q) {
        const float sum = s1[q];
        float ssd = s2[q] - sum * sum * (1.0f / 32.0f);
        ssd = ssd > 0.f ? ssd : 0.f;
        const float ls = sqrtf(ssd * (1.0f / 31.0f));
        tt += ls / gmb[(lane << 2) + q];
    }
#pragma unroll
    for (int s2r = 1; s2r < 64; s2r <<= 1) tt += __shfl_xor(tt, s2r);

    if (lane == 0) ld_out[(size_t)b * NN + i] = tt;
}

// one wave per point: exact rank (desc, index tie-break) + direct row gather
__global__ void k_rank_gather(const float* __restrict__ x, const float* __restrict__ coords,
                              const float* __restrict__ ld,
                              float* __restrict__ x_out, float* __restrict__ c_out) {
    const int b    = blockIdx.y;
    const int wid  = threadIdx.x >> 6;
    const int lane = threadIdx.x & 63;
    const int i    = blockIdx.x * 4 + wid;
    const float* lb = ld + (size_t)b * NN;
    const float di = lb[i];
    int cnt = 0;
    for (int t = 0; t < NN / 256; ++t) {
        const int j0 = t * 256 + (lane << 2);
        const float4 dv = *reinterpret_cast<const float4*>(lb + j0);
        cnt += (dv.x > di || (dv.x == di && (j0 + 0) < i)) ? 1 : 0;
        cnt += (dv.y > di || (dv.y == di && (j0 + 1) < i)) ? 1 : 0;
        cnt += (dv.z > di || (dv.z == di && (j0 + 2) < i)) ? 1 : 0;
        cnt += (dv.w > di || (dv.w == di && (j0 + 3) < i)) ? 1 : 0;
    }
#pragma unroll
    for (int s = 1; s < 64; s <<= 1) cnt += __shfl_xor(cnt, s);

    if (cnt < NKEEP) {
        const float4 v = *reinterpret_cast<const float4*>(x + ((size_t)b * NN + i) * EE + (lane << 2));
        *reinterpret_cast<float4*>(x_out + ((size_t)b * NKEEP + cnt) * EE + (lane << 2)) = v;
        if (lane < 2) {
            c_out[((size_t)b * 2 + lane) * NKEEP + cnt] = coords[((size_t)b * 2 + lane) * NN + i];
        }
    }
}

extern "C" void kernel_launch(void* const* d_in, const int* in_sizes, int n_in,
                              void* d_out, int out_size, void* d_ws, size_t ws_size,
                              hipStream_t stream) {
    const float* x      = (const float*)d_in[0];
    const float* coords = (const float*)d_in[1];

    float* out    = (float*)d_out;
    float* x_out  = out;                 // [2][4096][256]
    float* c_out  = out + 2097152;       // [2][2][4096][1]
    float* ld_out = out + 2113536;       // [2][8192]

    char*   ws    = (char*)d_ws;
    float*  part  = (float*)(ws);
    float*  gm    = (float*)(ws + 65536);
    int*    start = (int*)  (ws + 67584);
    float2* sc    = (float2*)(ws + 100384);
    int*    sj    = (int*)  (ws + 231456);

    k_pre        <<<66,            1024, 0, stream>>>(coords, x, start, sc, sj, part);
    k_gm_final   <<<dim3(1, 2),    256,  0, stream>>>(part, gm);
    k_knn_dist   <<<4096,          256,  0, stream>>>(x, gm, sc, sj, start, ld_out);
    k_rank_gather<<<dim3(2048, 2), 256,  0, stream>>>(x, coords, ld_out, x_out, c_out);
}